// Round 2
// baseline (12423.643 us; speedup 1.0000x reference)
//
#include <hip/hip_runtime.h>
#include <stdint.h>

// Problem constants: B=64, T=512, I=256, H=512, L=2
#define Bn 64
#define Tn 512
#define In 256
#define Hn 512
#define NBLK 64                    // 32 blocks layer0 + 32 blocks layer1
#define OUT_HT 16777216            // B*T*H  (start of hT)
#define OUT_CT 16842752            // OUT_HT + 2*B*H (start of cT)

// Workspace layout (bytes):
//   0        h0buf[2][B][H] bf16   (131072)
//   131072   h1buf[2][B][H] bf16   (131072)
//   262144   barrier counters      (4096; 1024 uints, use [0..511])
//   266240   wx0 bf16 (2048x256)   (1048576)
//   1314816  wh0 bf16 (2048x512)   (2097152)
//   3411968  wx1 bf16 (2048x512)   (2097152)
//   5509120  wh1 bf16 (2048x512)   (2097152)

typedef __attribute__((ext_vector_type(8))) short bf16x8;
typedef __attribute__((ext_vector_type(4))) float f32x4;
typedef unsigned long long u64;

__device__ __forceinline__ unsigned short f2bf(float f) {   // fp32 -> bf16 RNE
    unsigned u = __float_as_uint(f);
    return (unsigned short)((u + 0x7fffu + ((u >> 16) & 1u)) >> 16);
}
__device__ __forceinline__ float sigm(float v) { return 1.0f / (1.0f + __expf(-v)); }
__device__ __forceinline__ float tanhv(float v) { float e = __expf(2.0f * v); return 1.0f - 2.0f / (e + 1.0f); }

// L3-coherent (cross-XCD) access: relaxed agent-scope atomics compile to
// global_load/store ... sc0 sc1 — bypass the incoherent per-XCD L1/L2,
// coherent at the memory-side Infinity Cache. Relaxed => no waitcnt
// serialization; loads pipeline freely.
__device__ __forceinline__ u64 ldg_coh(const u64* p) {
    return __hip_atomic_load((const u64*)p, __ATOMIC_RELAXED, __HIP_MEMORY_SCOPE_AGENT);
}
__device__ __forceinline__ void stg_coh(unsigned short* p, unsigned short v) {
    __hip_atomic_store(p, v, __ATOMIC_RELAXED, __HIP_MEMORY_SCOPE_AGENT);
}

union frag8 { bf16x8 v; u64 q[2]; };

__global__ void lstm_prep(const float* __restrict__ wxh0, const float* __restrict__ whh0,
                          const float* __restrict__ wxh1, const float* __restrict__ whh1,
                          unsigned short* __restrict__ wx0b, unsigned short* __restrict__ wh0b,
                          unsigned short* __restrict__ wx1b, unsigned short* __restrict__ wh1b,
                          unsigned int* __restrict__ zr) {
    int tid = blockIdx.x * blockDim.x + threadIdx.x;
    int stride = gridDim.x * blockDim.x;
    for (int n = tid; n < 2048 * 256; n += stride) wx0b[n] = f2bf(wxh0[n]);
    for (int n = tid; n < 2048 * 512; n += stride) {
        wh0b[n] = f2bf(whh0[n]);
        wx1b[n] = f2bf(wxh1[n]);
        wh1b[n] = f2bf(whh1[n]);
    }
    // zero h double-buffers + barrier counters: 266240/4 = 66560 uints
    for (int n = tid; n < 66560; n += stride) zr[n] = 0u;
}

__launch_bounds__(256, 1)
__global__ void lstm_main(const float* __restrict__ x,
                          const unsigned short* __restrict__ wx0,
                          const unsigned short* __restrict__ wh0,
                          const unsigned short* __restrict__ wx1,
                          const unsigned short* __restrict__ wh1,
                          const float* __restrict__ bx0, const float* __restrict__ bh0,
                          const float* __restrict__ bx1, const float* __restrict__ bh1,
                          float* __restrict__ out,
                          unsigned short* __restrict__ h0b,
                          unsigned short* __restrict__ h1b,
                          unsigned int* __restrict__ bar) {
    const int layer = blockIdx.x >> 5;        // 0 or 1
    const int cb    = blockIdx.x & 31;        // owns h cols [cb*16, cb*16+16)
    const int wv    = threadIdx.x >> 6;       // wave -> row tile [16*wv, 16*wv+16)
    const int lane  = threadIdx.x & 63;
    const int quad  = lane >> 4;
    const int ln    = lane & 15;
    const int row0  = wv << 4;
    const int colh  = (cb << 4) + ln;

    float bias[4];
#pragma unroll
    for (int q = 0; q < 4; ++q) {
        int gc = q * Hn + colh;
        bias[q] = (layer == 0) ? (bx0[gc] + bh0[gc]) : (bx1[gc] + bh1[gc]);
    }

    // B-fragment base pointers (weights: plain cached loads, L2-resident)
    const unsigned short* wbp[4];
    const unsigned short* whp[4];
#pragma unroll
    for (int q = 0; q < 4; ++q) {
        int gc = q * Hn + colh;
        wbp[q] = (layer == 0) ? (wx0 + (size_t)gc * In + quad * 8)
                              : (wx1 + (size_t)gc * Hn + quad * 8);
        whp[q] = ((layer == 0) ? wh0 : wh1) + (size_t)gc * Hn + quad * 8;
    }

    const float* xrow0 = x + (size_t)(row0 + ln) * Tn * In + quad * 8;
    const int hoff = (row0 + ln) * Hn + quad * 8;   // element offset; *2 bytes is 16B-aligned

    float c[4] = {0.f, 0.f, 0.f, 0.f};

    for (int p = 0; p <= Tn; ++p) {
        const int t = (layer == 0) ? p : (p - 1);
        const bool active = (layer == 0) ? (p < Tn) : (p >= 1);
        const int wrb = p & 1;
        const int rdb = wrb ^ 1;

        if (active) {
            f32x4 acc[4];
#pragma unroll
            for (int q = 0; q < 4; ++q) acc[q] = (f32x4){bias[q], bias[q], bias[q], bias[q]};

            if (layer == 0) {
                // ---- preload all A fragments (bulk, latencies overlap) ----
                frag8 ax[8];                       // x part, K=256, fp32->bf16
                const float* xr = xrow0 + (size_t)t * In;
#pragma unroll
                for (int i = 0; i < 8; ++i) {
                    f32x4 xa = *(const f32x4*)(xr + i * 32);
                    f32x4 xc = *(const f32x4*)(xr + i * 32 + 4);
                    ax[i].v[0] = (short)f2bf(xa[0]); ax[i].v[1] = (short)f2bf(xa[1]);
                    ax[i].v[2] = (short)f2bf(xa[2]); ax[i].v[3] = (short)f2bf(xa[3]);
                    ax[i].v[4] = (short)f2bf(xc[0]); ax[i].v[5] = (short)f2bf(xc[1]);
                    ax[i].v[6] = (short)f2bf(xc[2]); ax[i].v[7] = (short)f2bf(xc[3]);
                }
                frag8 ah[16];                      // h part, K=512, L3-coherent loads
                const u64* hp = (const u64*)(h0b + rdb * (Bn * Hn)) + (hoff >> 2);
#pragma unroll
                for (int i = 0; i < 16; ++i) {
                    ah[i].q[0] = ldg_coh(hp + i * 8);
                    ah[i].q[1] = ldg_coh(hp + i * 8 + 1);
                }
                // ---- MFMA ----
#pragma unroll
                for (int i = 0; i < 8; ++i)
#pragma unroll
                    for (int q = 0; q < 4; ++q) {
                        bf16x8 b = *(const bf16x8*)(wbp[q] + i * 32);
                        acc[q] = __builtin_amdgcn_mfma_f32_16x16x32_bf16(ax[i].v, b, acc[q], 0, 0, 0);
                    }
#pragma unroll
                for (int i = 0; i < 16; ++i)
#pragma unroll
                    for (int q = 0; q < 4; ++q) {
                        bf16x8 b = *(const bf16x8*)(whp[q] + i * 32);
                        acc[q] = __builtin_amdgcn_mfma_f32_16x16x32_bf16(ah[i].v, b, acc[q], 0, 0, 0);
                    }
            } else {
                frag8 a0[16], a1[16];
                const u64* p0 = (const u64*)(h0b + rdb * (Bn * Hn)) + (hoff >> 2);
                const u64* p1 = (const u64*)(h1b + rdb * (Bn * Hn)) + (hoff >> 2);
#pragma unroll
                for (int i = 0; i < 16; ++i) {
                    a0[i].q[0] = ldg_coh(p0 + i * 8);
                    a0[i].q[1] = ldg_coh(p0 + i * 8 + 1);
                    a1[i].q[0] = ldg_coh(p1 + i * 8);
                    a1[i].q[1] = ldg_coh(p1 + i * 8 + 1);
                }
#pragma unroll
                for (int i = 0; i < 16; ++i)
#pragma unroll
                    for (int q = 0; q < 4; ++q) {
                        bf16x8 b = *(const bf16x8*)(wbp[q] + i * 32);
                        acc[q] = __builtin_amdgcn_mfma_f32_16x16x32_bf16(a0[i].v, b, acc[q], 0, 0, 0);
                    }
#pragma unroll
                for (int i = 0; i < 16; ++i)
#pragma unroll
                    for (int q = 0; q < 4; ++q) {
                        bf16x8 b = *(const bf16x8*)(whp[q] + i * 32);
                        acc[q] = __builtin_amdgcn_mfma_f32_16x16x32_bf16(a1[i].v, b, acc[q], 0, 0, 0);
                    }
            }

            // ---- LSTM cell epilogue (per-lane) ----
            unsigned short* hw = ((layer == 0) ? h0b : h1b) + wrb * (Bn * Hn);
#pragma unroll
            for (int r = 0; r < 4; ++r) {
                int row = row0 + quad * 4 + r;
                float ig = sigm(acc[0][r]);
                float fg = sigm(acc[1][r]);
                float gg = tanhv(acc[2][r]);
                float og = sigm(acc[3][r]);
                float cy = c[r] * fg + ig * gg;
                float hy = og * tanhv(cy);
                c[r] = cy;
                stg_coh(hw + row * Hn + colh, f2bf(hy));       // L3-coherent h write
                if (layer == 1) out[(size_t)row * (Tn * Hn) + (size_t)t * Hn + colh] = hy;
                if (t == Tn - 1) {
                    out[OUT_HT + layer * (Bn * Hn) + row * Hn + colh] = hy;
                    out[OUT_CT + layer * (Bn * Hn) + row * Hn + colh] = cy;
                }
            }
        }

        // ---- grid barrier: NO cache-maintenance fences ----
        // __syncthreads() drains vmcnt for every wave (sc1 stores then sit at the
        // coherent L3), so a relaxed agent atomicAdd afterwards publishes them.
        if (p < Tn) {
            __syncthreads();
            if (threadIdx.x == 0) {
                __hip_atomic_fetch_add(&bar[p], 1u, __ATOMIC_RELAXED, __HIP_MEMORY_SCOPE_AGENT);
                while (__hip_atomic_load(&bar[p], __ATOMIC_RELAXED, __HIP_MEMORY_SCOPE_AGENT)
                       < (unsigned)gridDim.x) {
                    __builtin_amdgcn_s_sleep(1);
                }
            }
            __syncthreads();
        }
    }
}

extern "C" void kernel_launch(void* const* d_in, const int* in_sizes, int n_in,
                              void* d_out, int out_size, void* d_ws, size_t ws_size,
                              hipStream_t stream) {
    const float* x    = (const float*)d_in[0];
    const float* wxh0 = (const float*)d_in[1];
    const float* bxh0 = (const float*)d_in[2];
    const float* whh0 = (const float*)d_in[3];
    const float* bhh0 = (const float*)d_in[4];
    const float* wxh1 = (const float*)d_in[5];
    const float* bxh1 = (const float*)d_in[6];
    const float* whh1 = (const float*)d_in[7];
    const float* bhh1 = (const float*)d_in[8];
    float* out = (float*)d_out;

    char* ws = (char*)d_ws;
    unsigned short* h0b  = (unsigned short*)(ws);
    unsigned short* h1b  = (unsigned short*)(ws + 131072);
    unsigned int*   bar  = (unsigned int*)(ws + 262144);
    unsigned short* wx0b = (unsigned short*)(ws + 266240);
    unsigned short* wh0b = (unsigned short*)(ws + 1314816);
    unsigned short* wx1b = (unsigned short*)(ws + 3411968);
    unsigned short* wh1b = (unsigned short*)(ws + 5509120);

    lstm_prep<<<dim3(512), dim3(256), 0, stream>>>(
        wxh0, whh0, wxh1, whh1, wx0b, wh0b, wx1b, wh1b, (unsigned int*)ws);

    lstm_main<<<dim3(NBLK), dim3(256), 0, stream>>>(
        x, wx0b, wh0b, wx1b, wh1b, bxh0, bhh0, bxh1, bhh1,
        out, h0b, h1b, bar);
}

// Round 3
// 11698.972 us; speedup vs baseline: 1.0619x; 1.0619x over previous
//
#include <hip/hip_runtime.h>
#include <stdint.h>

// Problem constants: B=64, T=512, I=256, H=512, L=2
#define Bn 64
#define Tn 512
#define In 256
#define Hn 512
#define NBLK 64                    // 32 blocks layer0 + 32 blocks layer1
#define OUT_HT 16777216            // B*T*H  (start of hT)
#define OUT_CT 16842752            // OUT_HT + 2*B*H (start of cT)

// Workspace layout (bytes):
//   0        h0buf[2][B][H] bf16   (131072)
//   131072   h1buf[2][B][H] bf16   (131072)
//   262144   barrier flags         (4096; flag[b] at uint index b*16 — 64B apart)
//   266240   wx0 bf16 (2048x256)   (1048576)
//   1314816  wh0 bf16 (2048x512)   (2097152)
//   3411968  wx1 bf16 (2048x512)   (2097152)
//   5509120  wh1 bf16 (2048x512)   (2097152)

typedef __attribute__((ext_vector_type(8))) short bf16x8;
typedef __attribute__((ext_vector_type(4))) float f32x4;
typedef unsigned long long u64;

__device__ __forceinline__ unsigned short f2bf(float f) {   // fp32 -> bf16 RNE
    unsigned u = __float_as_uint(f);
    return (unsigned short)((u + 0x7fffu + ((u >> 16) & 1u)) >> 16);
}
__device__ __forceinline__ float sigm(float v) { return 1.0f / (1.0f + __expf(-v)); }
__device__ __forceinline__ float tanhv(float v) { float e = __expf(2.0f * v); return 1.0f - 2.0f / (e + 1.0f); }

// L3-coherent (cross-XCD) access: relaxed agent-scope atomics emit sc0/sc1
// global ops — bypass incoherent per-XCD L1/L2, coherent at Infinity Cache.
__device__ __forceinline__ u64 ldg_coh(const u64* p) {
    return __hip_atomic_load(p, __ATOMIC_RELAXED, __HIP_MEMORY_SCOPE_AGENT);
}
__device__ __forceinline__ void stg_coh(unsigned short* p, unsigned short v) {
    __hip_atomic_store(p, v, __ATOMIC_RELAXED, __HIP_MEMORY_SCOPE_AGENT);
}
__device__ __forceinline__ unsigned ld_flag(const unsigned* p) {
    return __hip_atomic_load(p, __ATOMIC_RELAXED, __HIP_MEMORY_SCOPE_AGENT);
}
__device__ __forceinline__ void st_flag(unsigned* p, unsigned v) {
    __hip_atomic_store(p, v, __ATOMIC_RELAXED, __HIP_MEMORY_SCOPE_AGENT);
}

union frag8 { bf16x8 v; u64 q[2]; };

__global__ void lstm_prep(const float* __restrict__ wxh0, const float* __restrict__ whh0,
                          const float* __restrict__ wxh1, const float* __restrict__ whh1,
                          unsigned short* __restrict__ wx0b, unsigned short* __restrict__ wh0b,
                          unsigned short* __restrict__ wx1b, unsigned short* __restrict__ wh1b,
                          unsigned int* __restrict__ zr) {
    int tid = blockIdx.x * blockDim.x + threadIdx.x;
    int stride = gridDim.x * blockDim.x;
    for (int n = tid; n < 2048 * 256; n += stride) wx0b[n] = f2bf(wxh0[n]);
    for (int n = tid; n < 2048 * 512; n += stride) {
        wh0b[n] = f2bf(whh0[n]);
        wx1b[n] = f2bf(wxh1[n]);
        wh1b[n] = f2bf(whh1[n]);
    }
    // zero h double-buffers + barrier flags: 266240/4 = 66560 uints
    for (int n = tid; n < 66560; n += stride) zr[n] = 0u;
}

__launch_bounds__(256, 1)
__global__ void lstm_main(const float* __restrict__ x,
                          const unsigned short* __restrict__ wx0,
                          const unsigned short* __restrict__ wh0,
                          const unsigned short* __restrict__ wx1,
                          const unsigned short* __restrict__ wh1,
                          const float* __restrict__ bx0, const float* __restrict__ bh0,
                          const float* __restrict__ bx1, const float* __restrict__ bh1,
                          float* __restrict__ out,
                          unsigned short* __restrict__ h0b,
                          unsigned short* __restrict__ h1b,
                          unsigned int* __restrict__ bar) {
    const int layer = blockIdx.x >> 5;        // 0 or 1
    const int cb    = blockIdx.x & 31;        // owns h cols [cb*16, cb*16+16)
    const int wv    = threadIdx.x >> 6;       // wave -> row tile [16*wv, 16*wv+16)
    const int lane  = threadIdx.x & 63;
    const int quad  = lane >> 4;
    const int ln    = lane & 15;
    const int row0  = wv << 4;
    const int colh  = (cb << 4) + ln;

    float bias[4];
#pragma unroll
    for (int q = 0; q < 4; ++q) {
        int gc = q * Hn + colh;
        bias[q] = (layer == 0) ? (bx0[gc] + bh0[gc]) : (bx1[gc] + bh1[gc]);
    }

    // B-fragment base pointers (weights: plain cached loads, L2-resident)
    const unsigned short* wbp[4];
    const unsigned short* whp[4];
#pragma unroll
    for (int q = 0; q < 4; ++q) {
        int gc = q * Hn + colh;
        wbp[q] = (layer == 0) ? (wx0 + (size_t)gc * In + quad * 8)
                              : (wx1 + (size_t)gc * Hn + quad * 8);
        whp[q] = ((layer == 0) ? wh0 : wh1) + (size_t)gc * Hn + quad * 8;
    }

    const float* xrow0 = x + (size_t)(row0 + ln) * Tn * In + quad * 8;
    const int hoff = (row0 + ln) * Hn + quad * 8;

    float c[4] = {0.f, 0.f, 0.f, 0.f};

    for (int p = 0; p <= Tn; ++p) {
        const int t = (layer == 0) ? p : (p - 1);
        const bool active = (layer == 0) ? (p < Tn) : (p >= 1);
        const int wrb = p & 1;
        const int rdb = wrb ^ 1;

        if (active) {
            f32x4 acc[4];
#pragma unroll
            for (int q = 0; q < 4; ++q) acc[q] = (f32x4){bias[q], bias[q], bias[q], bias[q]};

            if (layer == 0) {
                // ---- preload all A fragments (bulk, latencies overlap) ----
                frag8 ax[8];                       // x part, K=256, fp32->bf16
                const float* xr = xrow0 + (size_t)t * In;
#pragma unroll
                for (int i = 0; i < 8; ++i) {
                    f32x4 xa = *(const f32x4*)(xr + i * 32);
                    f32x4 xc = *(const f32x4*)(xr + i * 32 + 4);
                    ax[i].v[0] = (short)f2bf(xa[0]); ax[i].v[1] = (short)f2bf(xa[1]);
                    ax[i].v[2] = (short)f2bf(xa[2]); ax[i].v[3] = (short)f2bf(xa[3]);
                    ax[i].v[4] = (short)f2bf(xc[0]); ax[i].v[5] = (short)f2bf(xc[1]);
                    ax[i].v[6] = (short)f2bf(xc[2]); ax[i].v[7] = (short)f2bf(xc[3]);
                }
                frag8 ah[16];                      // h part, K=512, L3-coherent loads
                const u64* hp = (const u64*)(h0b + rdb * (Bn * Hn)) + (hoff >> 2);
#pragma unroll
                for (int i = 0; i < 16; ++i) {
                    ah[i].q[0] = ldg_coh(hp + i * 8);
                    ah[i].q[1] = ldg_coh(hp + i * 8 + 1);
                }
#pragma unroll
                for (int i = 0; i < 8; ++i)
#pragma unroll
                    for (int q = 0; q < 4; ++q) {
                        bf16x8 b = *(const bf16x8*)(wbp[q] + i * 32);
                        acc[q] = __builtin_amdgcn_mfma_f32_16x16x32_bf16(ax[i].v, b, acc[q], 0, 0, 0);
                    }
#pragma unroll
                for (int i = 0; i < 16; ++i)
#pragma unroll
                    for (int q = 0; q < 4; ++q) {
                        bf16x8 b = *(const bf16x8*)(whp[q] + i * 32);
                        acc[q] = __builtin_amdgcn_mfma_f32_16x16x32_bf16(ah[i].v, b, acc[q], 0, 0, 0);
                    }
            } else {
                frag8 a0[16], a1[16];
                const u64* p0 = (const u64*)(h0b + rdb * (Bn * Hn)) + (hoff >> 2);
                const u64* p1 = (const u64*)(h1b + rdb * (Bn * Hn)) + (hoff >> 2);
#pragma unroll
                for (int i = 0; i < 16; ++i) {
                    a0[i].q[0] = ldg_coh(p0 + i * 8);
                    a0[i].q[1] = ldg_coh(p0 + i * 8 + 1);
                    a1[i].q[0] = ldg_coh(p1 + i * 8);
                    a1[i].q[1] = ldg_coh(p1 + i * 8 + 1);
                }
#pragma unroll
                for (int i = 0; i < 16; ++i)
#pragma unroll
                    for (int q = 0; q < 4; ++q) {
                        bf16x8 b = *(const bf16x8*)(wbp[q] + i * 32);
                        acc[q] = __builtin_amdgcn_mfma_f32_16x16x32_bf16(a0[i].v, b, acc[q], 0, 0, 0);
                    }
#pragma unroll
                for (int i = 0; i < 16; ++i)
#pragma unroll
                    for (int q = 0; q < 4; ++q) {
                        bf16x8 b = *(const bf16x8*)(whp[q] + i * 32);
                        acc[q] = __builtin_amdgcn_mfma_f32_16x16x32_bf16(a1[i].v, b, acc[q], 0, 0, 0);
                    }
            }

            // ---- LSTM cell epilogue (per-lane) ----
            unsigned short* hw = ((layer == 0) ? h0b : h1b) + wrb * (Bn * Hn);
#pragma unroll
            for (int r = 0; r < 4; ++r) {
                int row = row0 + quad * 4 + r;
                float ig = sigm(acc[0][r]);
                float fg = sigm(acc[1][r]);
                float gg = tanhv(acc[2][r]);
                float og = sigm(acc[3][r]);
                float cy = c[r] * fg + ig * gg;
                float hy = og * tanhv(cy);
                c[r] = cy;
                stg_coh(hw + row * Hn + colh, f2bf(hy));       // L3-coherent h write
                if (layer == 1) out[(size_t)row * (Tn * Hn) + (size_t)t * Hn + colh] = hy;
                if (t == Tn - 1) {
                    out[OUT_HT + layer * (Bn * Hn) + row * Hn + colh] = hy;
                    out[OUT_CT + layer * (Bn * Hn) + row * Hn + colh] = cy;
                }
            }
        }

        // ---- grid barrier: store-flag + all-gather poll. NO atomic RMW. ----
        // __syncthreads() drains every wave's vmcnt, so all sc1 h-stores have
        // reached the coherent L3 before the flag store is issued.
        // flag[b] lives at bar[b*16] (64 B apart -> no cacheline sharing; 64
        // parallel stores, no serialization). Every block's wave 0 polls all
        // 64 flags (one lane per flag) and exits on __all(flag > p).
        if (p < Tn) {
            __syncthreads();
            if (threadIdx.x == 0) st_flag(&bar[(unsigned)blockIdx.x * 16u], (unsigned)(p + 1));
            if (threadIdx.x < 64) {
                while (!__all(ld_flag(&bar[(unsigned)threadIdx.x * 16u]) > (unsigned)p)) { }
            }
            __syncthreads();
        }
    }
}

extern "C" void kernel_launch(void* const* d_in, const int* in_sizes, int n_in,
                              void* d_out, int out_size, void* d_ws, size_t ws_size,
                              hipStream_t stream) {
    const float* x    = (const float*)d_in[0];
    const float* wxh0 = (const float*)d_in[1];
    const float* bxh0 = (const float*)d_in[2];
    const float* whh0 = (const float*)d_in[3];
    const float* bhh0 = (const float*)d_in[4];
    const float* wxh1 = (const float*)d_in[5];
    const float* bxh1 = (const float*)d_in[6];
    const float* whh1 = (const float*)d_in[7];
    const float* bhh1 = (const float*)d_in[8];
    float* out = (float*)d_out;

    char* ws = (char*)d_ws;
    unsigned short* h0b  = (unsigned short*)(ws);
    unsigned short* h1b  = (unsigned short*)(ws + 131072);
    unsigned int*   bar  = (unsigned int*)(ws + 262144);
    unsigned short* wx0b = (unsigned short*)(ws + 266240);
    unsigned short* wh0b = (unsigned short*)(ws + 1314816);
    unsigned short* wx1b = (unsigned short*)(ws + 3411968);
    unsigned short* wh1b = (unsigned short*)(ws + 5509120);

    lstm_prep<<<dim3(512), dim3(256), 0, stream>>>(
        wxh0, whh0, wxh1, whh1, wx0b, wh0b, wx1b, wh1b, (unsigned int*)ws);

    lstm_main<<<dim3(NBLK), dim3(256), 0, stream>>>(
        x, wx0b, wh0b, wx1b, wh1b, bxh0, bhh0, bxh1, bhh1,
        out, h0b, h1b, bar);
}

// Round 4
// 5281.266 us; speedup vs baseline: 2.3524x; 2.2152x over previous
//
#include <hip/hip_runtime.h>
#include <stdint.h>

// Problem constants: B=64, T=512, I=256, H=512, L=2
#define Bn 64
#define Tn 512
#define In 256
#define Hn 512
#define NBLK 64                    // 32 blocks layer0 + 32 blocks layer1
#define OUT_HT 16777216            // B*T*H  (start of hT)
#define OUT_CT 16842752            // OUT_HT + 2*B*H (start of cT)
#define LDS_BYTES 131072           // layer1: 64KB wx1-frags + 64KB wh1-frags

// Workspace layout (bytes):
//   0        h0buf[2][B][H] bf16   (131072)
//   131072   h1buf[2][B][H] bf16   (131072)
//   262144   barrier flags         (4096; flag[b] at uint index b*16 — 64B apart)
//   266240   wx0 bf16 (2048x256)   (1048576)
//   1314816  wh0 bf16 (2048x512)   (2097152)
//   3411968  wx1 bf16 (2048x512)   (2097152)
//   5509120  wh1 bf16 (2048x512)   (2097152)

typedef __attribute__((ext_vector_type(8))) short bf16x8;
typedef __attribute__((ext_vector_type(4))) float f32x4;
typedef unsigned long long u64;

__device__ __forceinline__ unsigned short f2bf(float f) {   // fp32 -> bf16 RNE
    unsigned u = __float_as_uint(f);
    return (unsigned short)((u + 0x7fffu + ((u >> 16) & 1u)) >> 16);
}
__device__ __forceinline__ float sigm(float v) { return 1.0f / (1.0f + __expf(-v)); }
__device__ __forceinline__ float tanhv(float v) { float e = __expf(2.0f * v); return 1.0f - 2.0f / (e + 1.0f); }

// L3-coherent (cross-XCD) access: relaxed agent-scope atomics emit sc0/sc1
// global ops — bypass incoherent per-XCD L1/L2, coherent at Infinity Cache.
__device__ __forceinline__ u64 ldg_coh(const u64* p) {
    return __hip_atomic_load(p, __ATOMIC_RELAXED, __HIP_MEMORY_SCOPE_AGENT);
}
__device__ __forceinline__ void stg_coh(unsigned short* p, unsigned short v) {
    __hip_atomic_store(p, v, __ATOMIC_RELAXED, __HIP_MEMORY_SCOPE_AGENT);
}
__device__ __forceinline__ unsigned ld_flag(const unsigned* p) {
    return __hip_atomic_load(p, __ATOMIC_RELAXED, __HIP_MEMORY_SCOPE_AGENT);
}
__device__ __forceinline__ void st_flag(unsigned* p, unsigned v) {
    __hip_atomic_store(p, v, __ATOMIC_RELAXED, __HIP_MEMORY_SCOPE_AGENT);
}

union frag8 { bf16x8 v; u64 q[2]; };

__global__ void lstm_prep(const float* __restrict__ wxh0, const float* __restrict__ whh0,
                          const float* __restrict__ wxh1, const float* __restrict__ whh1,
                          unsigned short* __restrict__ wx0b, unsigned short* __restrict__ wh0b,
                          unsigned short* __restrict__ wx1b, unsigned short* __restrict__ wh1b,
                          unsigned int* __restrict__ zr) {
    int tid = blockIdx.x * blockDim.x + threadIdx.x;
    int stride = gridDim.x * blockDim.x;
    for (int n = tid; n < 2048 * 256; n += stride) wx0b[n] = f2bf(wxh0[n]);
    for (int n = tid; n < 2048 * 512; n += stride) {
        wh0b[n] = f2bf(whh0[n]);
        wx1b[n] = f2bf(wxh1[n]);
        wh1b[n] = f2bf(whh1[n]);
    }
    // zero h double-buffers + barrier flags: 266240/4 = 66560 uints
    for (int n = tid; n < 66560; n += stride) zr[n] = 0u;
}

__launch_bounds__(256, 1)
__global__ void lstm_main(const float* __restrict__ x,
                          const unsigned short* __restrict__ wx0,
                          const unsigned short* __restrict__ wh0,
                          const unsigned short* __restrict__ wx1,
                          const unsigned short* __restrict__ wh1,
                          const float* __restrict__ bx0, const float* __restrict__ bh0,
                          const float* __restrict__ bx1, const float* __restrict__ bh1,
                          float* __restrict__ out,
                          unsigned short* __restrict__ h0b,
                          unsigned short* __restrict__ h1b,
                          unsigned int* __restrict__ bar) {
    extern __shared__ char smem[];                // weight fragments, staged once
    const int layer = blockIdx.x >> 5;            // 0 or 1
    const int cb    = blockIdx.x & 31;            // owns h cols [cb*16, cb*16+16)
    const int wv    = threadIdx.x >> 6;           // wave -> row tile [16*wv, 16*wv+16)
    const int lane  = threadIdx.x & 63;
    const int quad  = lane >> 4;
    const int ln    = lane & 15;
    const int row0  = wv << 4;
    const int colh  = (cb << 4) + ln;

    // ---- stage this block's weight slices into LDS, fragment-major ----
    // chunk c = (i*4+q)*64 + lane_in_wave; 16B per chunk; region0 = x-side
    // matrix (K0), region1 = h-side matrix (K=512). All per-phase B-reads
    // become ds_read_b128 of a contiguous 1KB/wave line — conflict-free.
    const int I0 = (layer == 0) ? 8 : 16;         // K0/32 iterations
    const int K0 = (layer == 0) ? In : Hn;
    const unsigned short* Wxs = (layer == 0) ? wx0 : wx1;
    const unsigned short* Whs = (layer == 0) ? wh0 : wh1;
    u64* sm64 = (u64*)smem;
    const int tot0 = I0 * 4 * 64;
    for (int c = threadIdx.x; c < tot0; c += 256) {
        int lc = c & 63, qg = (c >> 6) & 3, ii = c >> 8;
        const unsigned short* src = Wxs + (size_t)(qg * Hn + (cb << 4) + (lc & 15)) * K0
                                        + ii * 32 + (lc >> 4) * 8;
        sm64[c * 2]     = *(const u64*)(src);
        sm64[c * 2 + 1] = *(const u64*)(src + 4);
    }
    const int hbase = tot0;                       // chunk base of h-side region
    for (int c = threadIdx.x; c < 16 * 4 * 64; c += 256) {
        int lc = c & 63, qg = (c >> 6) & 3, ii = c >> 8;
        const unsigned short* src = Whs + (size_t)(qg * Hn + (cb << 4) + (lc & 15)) * Hn
                                        + ii * 32 + (lc >> 4) * 8;
        sm64[(hbase + c) * 2]     = *(const u64*)(src);
        sm64[(hbase + c) * 2 + 1] = *(const u64*)(src + 4);
    }
    __syncthreads();
    const bf16x8* bfr = (const bf16x8*)smem;      // chunk-indexed B fragments

    float bias[4];
#pragma unroll
    for (int q = 0; q < 4; ++q) {
        int gc = q * Hn + colh;
        bias[q] = (layer == 0) ? (bx0[gc] + bh0[gc]) : (bx1[gc] + bh1[gc]);
    }

    const float* xrow0 = x + (size_t)(row0 + ln) * Tn * In + quad * 8;
    const int hoff = (row0 + ln) * Hn + quad * 8;

    float c[4] = {0.f, 0.f, 0.f, 0.f};

    // layer0: x fragments for step t, prefetched one phase ahead
    frag8 axc[8];
    if (layer == 0) {
        const float* xr = xrow0;                  // t = 0
#pragma unroll
        for (int i = 0; i < 8; ++i) {
            f32x4 xa = *(const f32x4*)(xr + i * 32);
            f32x4 xc = *(const f32x4*)(xr + i * 32 + 4);
            axc[i].v[0] = (short)f2bf(xa[0]); axc[i].v[1] = (short)f2bf(xa[1]);
            axc[i].v[2] = (short)f2bf(xa[2]); axc[i].v[3] = (short)f2bf(xa[3]);
            axc[i].v[4] = (short)f2bf(xc[0]); axc[i].v[5] = (short)f2bf(xc[1]);
            axc[i].v[6] = (short)f2bf(xc[2]); axc[i].v[7] = (short)f2bf(xc[3]);
        }
    }

    for (int p = 0; p <= Tn; ++p) {
        const int t = (layer == 0) ? p : (p - 1);
        const bool active = (layer == 0) ? (p < Tn) : (p >= 1);
        const int wrb = p & 1;
        const int rdb = wrb ^ 1;

        if (active) {
            f32x4 acc[4];
#pragma unroll
            for (int q = 0; q < 4; ++q) acc[q] = (f32x4){bias[q], bias[q], bias[q], bias[q]};

            if (layer == 0) {
                // issue ALL h loads first (independent sc1 -> one L3 RTT)
                frag8 ah[16];
                const u64* hp = (const u64*)(h0b + rdb * (Bn * Hn)) + (hoff >> 2);
#pragma unroll
                for (int i = 0; i < 16; ++i) {
                    ah[i].q[0] = ldg_coh(hp + i * 8);
                    ah[i].q[1] = ldg_coh(hp + i * 8 + 1);
                }
                // x part: operands already in registers (prefetched), B from LDS
#pragma unroll
                for (int i = 0; i < 8; ++i)
#pragma unroll
                    for (int q = 0; q < 4; ++q)
                        acc[q] = __builtin_amdgcn_mfma_f32_16x16x32_bf16(
                            axc[i].v, bfr[(i * 4 + q) * 64 + lane], acc[q], 0, 0, 0);
                // h part
#pragma unroll
                for (int i = 0; i < 16; ++i)
#pragma unroll
                    for (int q = 0; q < 4; ++q)
                        acc[q] = __builtin_amdgcn_mfma_f32_16x16x32_bf16(
                            ah[i].v, bfr[hbase + (i * 4 + q) * 64 + lane], acc[q], 0, 0, 0);
            } else {
                frag8 a0[16], a1[16];
                const u64* p0 = (const u64*)(h0b + rdb * (Bn * Hn)) + (hoff >> 2);
                const u64* p1 = (const u64*)(h1b + rdb * (Bn * Hn)) + (hoff >> 2);
#pragma unroll
                for (int i = 0; i < 16; ++i) {
                    a0[i].q[0] = ldg_coh(p0 + i * 8);
                    a0[i].q[1] = ldg_coh(p0 + i * 8 + 1);
                    a1[i].q[0] = ldg_coh(p1 + i * 8);
                    a1[i].q[1] = ldg_coh(p1 + i * 8 + 1);
                }
#pragma unroll
                for (int i = 0; i < 16; ++i)
#pragma unroll
                    for (int q = 0; q < 4; ++q)
                        acc[q] = __builtin_amdgcn_mfma_f32_16x16x32_bf16(
                            a0[i].v, bfr[(i * 4 + q) * 64 + lane], acc[q], 0, 0, 0);
#pragma unroll
                for (int i = 0; i < 16; ++i)
#pragma unroll
                    for (int q = 0; q < 4; ++q)
                        acc[q] = __builtin_amdgcn_mfma_f32_16x16x32_bf16(
                            a1[i].v, bfr[hbase + (i * 4 + q) * 64 + lane], acc[q], 0, 0, 0);
            }

            // ---- LSTM cell epilogue (per-lane) ----
            unsigned short* hw = ((layer == 0) ? h0b : h1b) + wrb * (Bn * Hn);
#pragma unroll
            for (int r = 0; r < 4; ++r) {
                int row = row0 + quad * 4 + r;
                float ig = sigm(acc[0][r]);
                float fg = sigm(acc[1][r]);
                float gg = tanhv(acc[2][r]);
                float og = sigm(acc[3][r]);
                float cy = c[r] * fg + ig * gg;
                float hy = og * tanhv(cy);
                c[r] = cy;
                stg_coh(hw + row * Hn + colh, f2bf(hy));       // L3-coherent h write
                if (layer == 1) out[(size_t)row * (Tn * Hn) + (size_t)t * Hn + colh] = hy;
                if (t == Tn - 1) {
                    out[OUT_HT + layer * (Bn * Hn) + row * Hn + colh] = hy;
                    out[OUT_CT + layer * (Bn * Hn) + row * Hn + colh] = cy;
                }
            }

            // prefetch next step's x (off the inter-block critical path)
            if (layer == 0 && t + 1 < Tn) {
                const float* xr = xrow0 + (size_t)(t + 1) * In;
#pragma unroll
                for (int i = 0; i < 8; ++i) {
                    f32x4 xa = *(const f32x4*)(xr + i * 32);
                    f32x4 xc = *(const f32x4*)(xr + i * 32 + 4);
                    axc[i].v[0] = (short)f2bf(xa[0]); axc[i].v[1] = (short)f2bf(xa[1]);
                    axc[i].v[2] = (short)f2bf(xa[2]); axc[i].v[3] = (short)f2bf(xa[3]);
                    axc[i].v[4] = (short)f2bf(xc[0]); axc[i].v[5] = (short)f2bf(xc[1]);
                    axc[i].v[6] = (short)f2bf(xc[2]); axc[i].v[7] = (short)f2bf(xc[3]);
                }
            }
        }

        // ---- grid barrier: store-flag + all-gather poll (no atomic RMW) ----
        if (p < Tn) {
            __syncthreads();     // drains vmcnt: all sc1 h-stores at coherent L3
            if (threadIdx.x == 0) st_flag(&bar[(unsigned)blockIdx.x * 16u], (unsigned)(p + 1));
            if (threadIdx.x < 64) {
                while (!__all(ld_flag(&bar[(unsigned)threadIdx.x * 16u]) > (unsigned)p)) { }
            }
            __syncthreads();
        }
    }
}

extern "C" void kernel_launch(void* const* d_in, const int* in_sizes, int n_in,
                              void* d_out, int out_size, void* d_ws, size_t ws_size,
                              hipStream_t stream) {
    const float* x    = (const float*)d_in[0];
    const float* wxh0 = (const float*)d_in[1];
    const float* bxh0 = (const float*)d_in[2];
    const float* whh0 = (const float*)d_in[3];
    const float* bhh0 = (const float*)d_in[4];
    const float* wxh1 = (const float*)d_in[5];
    const float* bxh1 = (const float*)d_in[6];
    const float* whh1 = (const float*)d_in[7];
    const float* bhh1 = (const float*)d_in[8];
    float* out = (float*)d_out;

    char* ws = (char*)d_ws;
    unsigned short* h0b  = (unsigned short*)(ws);
    unsigned short* h1b  = (unsigned short*)(ws + 131072);
    unsigned int*   bar  = (unsigned int*)(ws + 262144);
    unsigned short* wx0b = (unsigned short*)(ws + 266240);
    unsigned short* wh0b = (unsigned short*)(ws + 1314816);
    unsigned short* wx1b = (unsigned short*)(ws + 3411968);
    unsigned short* wh1b = (unsigned short*)(ws + 5509120);

    // allow 128 KB dynamic LDS (gfx950: 160 KB/CU) — idempotent, capture-safe
    static int lds_attr_set = 0;
    if (!lds_attr_set) {
        hipFuncSetAttribute((const void*)lstm_main,
                            hipFuncAttributeMaxDynamicSharedMemorySize, LDS_BYTES);
        lds_attr_set = 1;
    }

    lstm_prep<<<dim3(512), dim3(256), 0, stream>>>(
        wxh0, whh0, wxh1, whh1, wx0b, wh0b, wx1b, wh1b, (unsigned int*)ws);

    lstm_main<<<dim3(NBLK), dim3(256), LDS_BYTES, stream>>>(
        x, wx0b, wh0b, wx1b, wh1b, bxh0, bhh0, bxh1, bhh1,
        out, h0b, h1b, bar);
}

// Round 5
// 4756.135 us; speedup vs baseline: 2.6121x; 1.1104x over previous
//
#include <hip/hip_runtime.h>
#include <stdint.h>

// Problem constants: B=64, T=512, I=256, H=512, L=2
#define Bn 64
#define Tn 512
#define In 256
#define Hn 512
#define NBLK 64                    // 32 blocks layer0 + 32 blocks layer1
#define OUT_HT 16777216            // B*T*H  (start of hT)
#define OUT_CT 16842752            // OUT_HT + 2*B*H (start of cT)
#define LDS_BYTES 131072           // layer1: 64KB wx1-frags + 64KB wh1-frags

// Workspace layout (bytes):
//   0        h0buf[2][B][H] bf16   (131072)
//   131072   h1buf[2][B][H] bf16   (131072)
//   262144   barrier flags         (4096; flag[b] at uint index b*16 — 64B apart)
//   266240   wx0 bf16 (2048x256)   (1048576)
//   1314816  wh0 bf16 (2048x512)   (2097152)
//   3411968  wx1 bf16 (2048x512)   (2097152)
//   5509120  wh1 bf16 (2048x512)   (2097152)

typedef __attribute__((ext_vector_type(8))) short bf16x8;
typedef __attribute__((ext_vector_type(4))) float f32x4;
typedef unsigned long long u64;

__device__ __forceinline__ unsigned short f2bf(float f) {   // fp32 -> bf16 RNE
    unsigned u = __float_as_uint(f);
    return (unsigned short)((u + 0x7fffu + ((u >> 16) & 1u)) >> 16);
}
__device__ __forceinline__ float sigm(float v) { return 1.0f / (1.0f + __expf(-v)); }
__device__ __forceinline__ float tanhv(float v) { float e = __expf(2.0f * v); return 1.0f - 2.0f / (e + 1.0f); }

// Barrier flags: sc1 accesses, coherent at L3 (bypass per-XCD L2).
__device__ __forceinline__ unsigned ld_flag(const unsigned* p) {
    return __hip_atomic_load(p, __ATOMIC_RELAXED, __HIP_MEMORY_SCOPE_AGENT);
}
__device__ __forceinline__ void st_flag(unsigned* p, unsigned v) {
    __hip_atomic_store(p, v, __ATOMIC_RELAXED, __HIP_MEMORY_SCOPE_AGENT);
}

__global__ void lstm_prep(const float* __restrict__ wxh0, const float* __restrict__ whh0,
                          const float* __restrict__ wxh1, const float* __restrict__ whh1,
                          unsigned short* __restrict__ wx0b, unsigned short* __restrict__ wh0b,
                          unsigned short* __restrict__ wx1b, unsigned short* __restrict__ wh1b,
                          unsigned int* __restrict__ zr) {
    int tid = blockIdx.x * blockDim.x + threadIdx.x;
    int stride = gridDim.x * blockDim.x;
    for (int n = tid; n < 2048 * 256; n += stride) wx0b[n] = f2bf(wxh0[n]);
    for (int n = tid; n < 2048 * 512; n += stride) {
        wh0b[n] = f2bf(whh0[n]);
        wx1b[n] = f2bf(wxh1[n]);
        wh1b[n] = f2bf(whh1[n]);
    }
    // zero h double-buffers + barrier flags: 266240/4 = 66560 uints
    for (int n = tid; n < 66560; n += stride) zr[n] = 0u;
}

__launch_bounds__(256, 1)
__global__ void lstm_main(const float* __restrict__ x,
                          const unsigned short* __restrict__ wx0,
                          const unsigned short* __restrict__ wh0,
                          const unsigned short* __restrict__ wx1,
                          const unsigned short* __restrict__ wh1,
                          const float* __restrict__ bx0, const float* __restrict__ bh0,
                          const float* __restrict__ bx1, const float* __restrict__ bh1,
                          float* __restrict__ out,
                          unsigned short* __restrict__ h0b,
                          unsigned short* __restrict__ h1b,
                          unsigned int* __restrict__ bar) {
    extern __shared__ char smem[];                // weight fragments, staged once
    const int layer = blockIdx.x >> 5;            // 0 or 1
    const int cb    = blockIdx.x & 31;            // owns h cols [cb*16, cb*16+16)
    const int wv    = threadIdx.x >> 6;           // wave -> row tile [16*wv, 16*wv+16)
    const int lane  = threadIdx.x & 63;
    const int quad  = lane >> 4;
    const int ln    = lane & 15;
    const int row0  = wv << 4;
    const int colh  = (cb << 4) + ln;

    // ---- stage this block's weight slices into LDS, fragment-major ----
    const int I0 = (layer == 0) ? 8 : 16;         // K0/32 iterations
    const int K0 = (layer == 0) ? In : Hn;
    const unsigned short* Wxs = (layer == 0) ? wx0 : wx1;
    const unsigned short* Whs = (layer == 0) ? wh0 : wh1;
    u64* sm64 = (u64*)smem;
    const int tot0 = I0 * 4 * 64;
    for (int c = threadIdx.x; c < tot0; c += 256) {
        int lc = c & 63, qg = (c >> 6) & 3, ii = c >> 8;
        const unsigned short* src = Wxs + (size_t)(qg * Hn + (cb << 4) + (lc & 15)) * K0
                                        + ii * 32 + (lc >> 4) * 8;
        sm64[c * 2]     = *(const u64*)(src);
        sm64[c * 2 + 1] = *(const u64*)(src + 4);
    }
    const int hbase = tot0;                       // chunk base of h-side region
    for (int c = threadIdx.x; c < 16 * 4 * 64; c += 256) {
        int lc = c & 63, qg = (c >> 6) & 3, ii = c >> 8;
        const unsigned short* src = Whs + (size_t)(qg * Hn + (cb << 4) + (lc & 15)) * Hn
                                        + ii * 32 + (lc >> 4) * 8;
        sm64[(hbase + c) * 2]     = *(const u64*)(src);
        sm64[(hbase + c) * 2 + 1] = *(const u64*)(src + 4);
    }
    __syncthreads();
    const bf16x8* bfr = (const bf16x8*)smem;      // chunk-indexed B fragments

    float bias[4];
#pragma unroll
    for (int q = 0; q < 4; ++q) {
        int gc = q * Hn + colh;
        bias[q] = (layer == 0) ? (bx0[gc] + bh0[gc]) : (bx1[gc] + bh1[gc]);
    }

    const float* xrow0 = x + (size_t)(row0 + ln) * Tn * In + quad * 8;
    const int hoff = (row0 + ln) * Hn + quad * 8;  // *2B = row*1024 + quad*16 -> 16B aligned

    float c[4] = {0.f, 0.f, 0.f, 0.f};

    // layer0: x fragments for step t, prefetched one phase ahead
    bf16x8 axc[8];
    if (layer == 0) {
        const float* xr = xrow0;                  // t = 0
#pragma unroll
        for (int i = 0; i < 8; ++i) {
            f32x4 xa = *(const f32x4*)(xr + i * 32);
            f32x4 xc = *(const f32x4*)(xr + i * 32 + 4);
            axc[i][0] = (short)f2bf(xa[0]); axc[i][1] = (short)f2bf(xa[1]);
            axc[i][2] = (short)f2bf(xa[2]); axc[i][3] = (short)f2bf(xa[3]);
            axc[i][4] = (short)f2bf(xc[0]); axc[i][5] = (short)f2bf(xc[1]);
            axc[i][6] = (short)f2bf(xc[2]); axc[i][7] = (short)f2bf(xc[3]);
        }
    }

    for (int p = 0; p <= Tn; ++p) {
        const int t = (layer == 0) ? p : (p - 1);
        const bool active = (layer == 0) ? (p < Tn) : (p >= 1);
        const int wrb = p & 1;
        const int rdb = wrb ^ 1;

        if (active) {
            f32x4 acc[4];
#pragma unroll
            for (int q = 0; q < 4; ++q) acc[q] = (f32x4){bias[q], bias[q], bias[q], bias[q]};

            if (layer == 0) {
                // h part A-frags: PLAIN 16B loads — compiler clusters them,
                // fine-grained vmcnt pipelining. Coherence via per-phase fences.
                const unsigned short* hr = h0b + rdb * (Bn * Hn) + hoff;
                bf16x8 ah[16];
#pragma unroll
                for (int i = 0; i < 16; ++i) ah[i] = *(const bf16x8*)(hr + i * 32);
                // x part: operands already in registers (prefetched), B from LDS
#pragma unroll
                for (int i = 0; i < 8; ++i)
#pragma unroll
                    for (int q = 0; q < 4; ++q)
                        acc[q] = __builtin_amdgcn_mfma_f32_16x16x32_bf16(
                            axc[i], bfr[(i * 4 + q) * 64 + lane], acc[q], 0, 0, 0);
#pragma unroll
                for (int i = 0; i < 16; ++i)
#pragma unroll
                    for (int q = 0; q < 4; ++q)
                        acc[q] = __builtin_amdgcn_mfma_f32_16x16x32_bf16(
                            ah[i], bfr[hbase + (i * 4 + q) * 64 + lane], acc[q], 0, 0, 0);
            } else {
                const unsigned short* h0r = h0b + rdb * (Bn * Hn) + hoff;
                const unsigned short* h1r = h1b + rdb * (Bn * Hn) + hoff;
                bf16x8 a0[16], a1[16];
#pragma unroll
                for (int i = 0; i < 16; ++i) {
                    a0[i] = *(const bf16x8*)(h0r + i * 32);
                    a1[i] = *(const bf16x8*)(h1r + i * 32);
                }
#pragma unroll
                for (int i = 0; i < 16; ++i)
#pragma unroll
                    for (int q = 0; q < 4; ++q)
                        acc[q] = __builtin_amdgcn_mfma_f32_16x16x32_bf16(
                            a0[i], bfr[(i * 4 + q) * 64 + lane], acc[q], 0, 0, 0);
#pragma unroll
                for (int i = 0; i < 16; ++i)
#pragma unroll
                    for (int q = 0; q < 4; ++q)
                        acc[q] = __builtin_amdgcn_mfma_f32_16x16x32_bf16(
                            a1[i], bfr[hbase + (i * 4 + q) * 64 + lane], acc[q], 0, 0, 0);
            }

            // ---- LSTM cell epilogue (per-lane), PLAIN stores (L2 write-back;
            // pushed to L3 by the release fence before the arrival flag) ----
            unsigned short* hw = ((layer == 0) ? h0b : h1b) + wrb * (Bn * Hn);
#pragma unroll
            for (int r = 0; r < 4; ++r) {
                int row = row0 + quad * 4 + r;
                float ig = sigm(acc[0][r]);
                float fg = sigm(acc[1][r]);
                float gg = tanhv(acc[2][r]);
                float og = sigm(acc[3][r]);
                float cy = c[r] * fg + ig * gg;
                float hy = og * tanhv(cy);
                c[r] = cy;
                hw[row * Hn + colh] = f2bf(hy);
                if (layer == 1) out[(size_t)row * (Tn * Hn) + (size_t)t * Hn + colh] = hy;
                if (t == Tn - 1) {
                    out[OUT_HT + layer * (Bn * Hn) + row * Hn + colh] = hy;
                    out[OUT_CT + layer * (Bn * Hn) + row * Hn + colh] = cy;
                }
            }
        }

        // ---- grid barrier: release-fence + flag, x-prefetch overlaps poll,
        //      acquire-fence (buffer_inv) after detect ----
        if (p < Tn) {
            __syncthreads();     // every wave's stores drained to (our XCD's) L2
            if (threadIdx.x == 0) {
                __builtin_amdgcn_fence(__ATOMIC_RELEASE, "agent");  // wbl2: L2 -> L3
                st_flag(&bar[(unsigned)blockIdx.x * 16u], (unsigned)(p + 1));
            }
            // prefetch next x while wave0 polls (read-only, off critical path)
            if (layer == 0 && p + 1 < Tn) {
                const float* xr = xrow0 + (size_t)(p + 1) * In;
#pragma unroll
                for (int i = 0; i < 8; ++i) {
                    f32x4 xa = *(const f32x4*)(xr + i * 32);
                    f32x4 xc = *(const f32x4*)(xr + i * 32 + 4);
                    axc[i][0] = (short)f2bf(xa[0]); axc[i][1] = (short)f2bf(xa[1]);
                    axc[i][2] = (short)f2bf(xa[2]); axc[i][3] = (short)f2bf(xa[3]);
                    axc[i][4] = (short)f2bf(xc[0]); axc[i][5] = (short)f2bf(xc[1]);
                    axc[i][6] = (short)f2bf(xc[2]); axc[i][7] = (short)f2bf(xc[3]);
                }
            }
            if (threadIdx.x < 64) {
                while (!__all(ld_flag(&bar[(unsigned)threadIdx.x * 16u]) > (unsigned)p)) { }
                // invalidate (clean) L1+L2 so next phase's plain h-loads see L3.
                // All dirty lines were written back by the release fence above.
                __builtin_amdgcn_fence(__ATOMIC_ACQUIRE, "agent");
            }
            __syncthreads();
        }
    }
}

extern "C" void kernel_launch(void* const* d_in, const int* in_sizes, int n_in,
                              void* d_out, int out_size, void* d_ws, size_t ws_size,
                              hipStream_t stream) {
    const float* x    = (const float*)d_in[0];
    const float* wxh0 = (const float*)d_in[1];
    const float* bxh0 = (const float*)d_in[2];
    const float* whh0 = (const float*)d_in[3];
    const float* bhh0 = (const float*)d_in[4];
    const float* wxh1 = (const float*)d_in[5];
    const float* bxh1 = (const float*)d_in[6];
    const float* whh1 = (const float*)d_in[7];
    const float* bhh1 = (const float*)d_in[8];
    float* out = (float*)d_out;

    char* ws = (char*)d_ws;
    unsigned short* h0b  = (unsigned short*)(ws);
    unsigned short* h1b  = (unsigned short*)(ws + 131072);
    unsigned int*   bar  = (unsigned int*)(ws + 262144);
    unsigned short* wx0b = (unsigned short*)(ws + 266240);
    unsigned short* wh0b = (unsigned short*)(ws + 1314816);
    unsigned short* wx1b = (unsigned short*)(ws + 3411968);
    unsigned short* wh1b = (unsigned short*)(ws + 5509120);

    // allow 128 KB dynamic LDS (gfx950: 160 KB/CU) — idempotent, capture-safe
    static int lds_attr_set = 0;
    if (!lds_attr_set) {
        hipFuncSetAttribute((const void*)lstm_main,
                            hipFuncAttributeMaxDynamicSharedMemorySize, LDS_BYTES);
        lds_attr_set = 1;
    }

    lstm_prep<<<dim3(512), dim3(256), 0, stream>>>(
        wxh0, whh0, wxh1, whh1, wx0b, wh0b, wx1b, wh1b, (unsigned int*)ws);

    lstm_main<<<dim3(NBLK), dim3(256), LDS_BYTES, stream>>>(
        x, wx0b, wh0b, wx1b, wh1b, bxh0, bhh0, bxh1, bhh1,
        out, h0b, h1b, bar);
}

// Round 6
// 4475.434 us; speedup vs baseline: 2.7760x; 1.0627x over previous
//
#include <hip/hip_runtime.h>
#include <stdint.h>

// Problem constants: B=64, T=512, I=256, H=512, L=2
#define Bn 64
#define Tn 512
#define In 256
#define Hn 512
#define NBLK 64                    // 32 blocks layer0 + 32 blocks layer1
#define OUT_HT 16777216            // B*T*H  (start of hT)
#define OUT_CT 16842752            // OUT_HT + 2*B*H (start of cT)
#define LDS_BYTES 131072           // layer1: 64KB wx1-frags + 64KB wh1-frags
#define SLOT_ELEMS (Bn * Hn)       // 32768 bf16 = 64KB per h slot

// Workspace layout (bytes):
//   0       flags: int flag0[32][4], flag1[32][4]  (1KB used, 4KB reserved)
//   4096    h0 ring: NSLOT slots × 64KB
//   ...     h1 ring: NSLOT slots × 64KB   (NSLOT from ws_size, clamped [3,513])
// Weights are converted fp32->bf16 during LDS staging — no global bf16 copy.

typedef __attribute__((ext_vector_type(8))) short bf16x8;
typedef __attribute__((ext_vector_type(4))) float f32x4;
typedef unsigned long long u64;

__device__ __forceinline__ unsigned short f2bf(float f) {   // fp32 -> bf16 RNE
    unsigned u = __float_as_uint(f);
    return (unsigned short)((u + 0x7fffu + ((u >> 16) & 1u)) >> 16);
}
__device__ __forceinline__ float sigm(float v) { return 1.0f / (1.0f + __expf(-v)); }
__device__ __forceinline__ float tanhv(float v) { float e = __expf(2.0f * v); return 1.0f - 2.0f / (e + 1.0f); }

// sc0/sc1 accesses: bypass per-XCD L1/L2, coherent at Infinity Cache (L3).
__device__ __forceinline__ void stg_coh(unsigned short* p, unsigned short v) {
    __hip_atomic_store(p, v, __ATOMIC_RELAXED, __HIP_MEMORY_SCOPE_AGENT);
}
__device__ __forceinline__ int ld_flag(const int* p) {
    return __hip_atomic_load(p, __ATOMIC_RELAXED, __HIP_MEMORY_SCOPE_AGENT);
}
__device__ __forceinline__ void st_flag(int* p, int v) {
    __hip_atomic_store(p, v, __ATOMIC_RELAXED, __HIP_MEMORY_SCOPE_AGENT);
}
__device__ __forceinline__ bf16x8 asbf(f32x4 v) {
    union { f32x4 f; bf16x8 h; } u; u.f = v; return u.h;
}

// Batched sc1 frag loads: all issued back-to-back, ONE waitcnt. Forces a
// single L3 round-trip regardless of compiler register heuristics.
#define GLD16(A, VA)                                                   \
  asm volatile(                                                        \
    "global_load_dwordx4 %0,  %16, off offset:0 sc0 sc1\n\t"          \
    "global_load_dwordx4 %1,  %16, off offset:64 sc0 sc1\n\t"         \
    "global_load_dwordx4 %2,  %16, off offset:128 sc0 sc1\n\t"        \
    "global_load_dwordx4 %3,  %16, off offset:192 sc0 sc1\n\t"        \
    "global_load_dwordx4 %4,  %16, off offset:256 sc0 sc1\n\t"        \
    "global_load_dwordx4 %5,  %16, off offset:320 sc0 sc1\n\t"        \
    "global_load_dwordx4 %6,  %16, off offset:384 sc0 sc1\n\t"        \
    "global_load_dwordx4 %7,  %16, off offset:448 sc0 sc1\n\t"        \
    "global_load_dwordx4 %8,  %16, off offset:512 sc0 sc1\n\t"        \
    "global_load_dwordx4 %9,  %16, off offset:576 sc0 sc1\n\t"        \
    "global_load_dwordx4 %10, %16, off offset:640 sc0 sc1\n\t"        \
    "global_load_dwordx4 %11, %16, off offset:704 sc0 sc1\n\t"        \
    "global_load_dwordx4 %12, %16, off offset:768 sc0 sc1\n\t"        \
    "global_load_dwordx4 %13, %16, off offset:832 sc0 sc1\n\t"        \
    "global_load_dwordx4 %14, %16, off offset:896 sc0 sc1\n\t"        \
    "global_load_dwordx4 %15, %16, off offset:960 sc0 sc1\n\t"        \
    "s_waitcnt vmcnt(0)"                                               \
    : "=&v"(A[0]), "=&v"(A[1]), "=&v"(A[2]), "=&v"(A[3]),              \
      "=&v"(A[4]), "=&v"(A[5]), "=&v"(A[6]), "=&v"(A[7]),              \
      "=&v"(A[8]), "=&v"(A[9]), "=&v"(A[10]), "=&v"(A[11]),            \
      "=&v"(A[12]), "=&v"(A[13]), "=&v"(A[14]), "=&v"(A[15])           \
    : "v"(VA) : "memory")

#define GLD32(A, B, VA, VB)                                            \
  asm volatile(                                                        \
    "global_load_dwordx4 %0,  %32, off offset:0 sc0 sc1\n\t"          \
    "global_load_dwordx4 %1,  %32, off offset:64 sc0 sc1\n\t"         \
    "global_load_dwordx4 %2,  %32, off offset:128 sc0 sc1\n\t"        \
    "global_load_dwordx4 %3,  %32, off offset:192 sc0 sc1\n\t"        \
    "global_load_dwordx4 %4,  %32, off offset:256 sc0 sc1\n\t"        \
    "global_load_dwordx4 %5,  %32, off offset:320 sc0 sc1\n\t"        \
    "global_load_dwordx4 %6,  %32, off offset:384 sc0 sc1\n\t"        \
    "global_load_dwordx4 %7,  %32, off offset:448 sc0 sc1\n\t"        \
    "global_load_dwordx4 %8,  %32, off offset:512 sc0 sc1\n\t"        \
    "global_load_dwordx4 %9,  %32, off offset:576 sc0 sc1\n\t"        \
    "global_load_dwordx4 %10, %32, off offset:640 sc0 sc1\n\t"        \
    "global_load_dwordx4 %11, %32, off offset:704 sc0 sc1\n\t"        \
    "global_load_dwordx4 %12, %32, off offset:768 sc0 sc1\n\t"        \
    "global_load_dwordx4 %13, %32, off offset:832 sc0 sc1\n\t"        \
    "global_load_dwordx4 %14, %32, off offset:896 sc0 sc1\n\t"        \
    "global_load_dwordx4 %15, %32, off offset:960 sc0 sc1\n\t"        \
    "global_load_dwordx4 %16, %33, off offset:0 sc0 sc1\n\t"          \
    "global_load_dwordx4 %17, %33, off offset:64 sc0 sc1\n\t"         \
    "global_load_dwordx4 %18, %33, off offset:128 sc0 sc1\n\t"        \
    "global_load_dwordx4 %19, %33, off offset:192 sc0 sc1\n\t"        \
    "global_load_dwordx4 %20, %33, off offset:256 sc0 sc1\n\t"        \
    "global_load_dwordx4 %21, %33, off offset:320 sc0 sc1\n\t"        \
    "global_load_dwordx4 %22, %33, off offset:384 sc0 sc1\n\t"        \
    "global_load_dwordx4 %23, %33, off offset:448 sc0 sc1\n\t"        \
    "global_load_dwordx4 %24, %33, off offset:512 sc0 sc1\n\t"        \
    "global_load_dwordx4 %25, %33, off offset:576 sc0 sc1\n\t"        \
    "global_load_dwordx4 %26, %33, off offset:640 sc0 sc1\n\t"        \
    "global_load_dwordx4 %27, %33, off offset:704 sc0 sc1\n\t"        \
    "global_load_dwordx4 %28, %33, off offset:768 sc0 sc1\n\t"        \
    "global_load_dwordx4 %29, %33, off offset:832 sc0 sc1\n\t"        \
    "global_load_dwordx4 %30, %33, off offset:896 sc0 sc1\n\t"        \
    "global_load_dwordx4 %31, %33, off offset:960 sc0 sc1\n\t"        \
    "s_waitcnt vmcnt(0)"                                               \
    : "=&v"(A[0]), "=&v"(A[1]), "=&v"(A[2]), "=&v"(A[3]),              \
      "=&v"(A[4]), "=&v"(A[5]), "=&v"(A[6]), "=&v"(A[7]),              \
      "=&v"(A[8]), "=&v"(A[9]), "=&v"(A[10]), "=&v"(A[11]),            \
      "=&v"(A[12]), "=&v"(A[13]), "=&v"(A[14]), "=&v"(A[15]),          \
      "=&v"(B[0]), "=&v"(B[1]), "=&v"(B[2]), "=&v"(B[3]),              \
      "=&v"(B[4]), "=&v"(B[5]), "=&v"(B[6]), "=&v"(B[7]),              \
      "=&v"(B[8]), "=&v"(B[9]), "=&v"(B[10]), "=&v"(B[11]),            \
      "=&v"(B[12]), "=&v"(B[13]), "=&v"(B[14]), "=&v"(B[15])           \
    : "v"(VA), "v"(VB) : "memory")

__global__ void lstm_prep(u64* __restrict__ z0, u64* __restrict__ z1,
                          int* __restrict__ fl) {
    int tid = blockIdx.x * blockDim.x + threadIdx.x;
    if (tid < 256) st_flag(fl + tid, 0);
    // zero slot 0 of both h rings (h(-1) = 0) with sc1 stores -> land in L3
    for (int i = tid; i < SLOT_ELEMS / 4; i += gridDim.x * blockDim.x) {
        __hip_atomic_store(z0 + i, (u64)0, __ATOMIC_RELAXED, __HIP_MEMORY_SCOPE_AGENT);
        __hip_atomic_store(z1 + i, (u64)0, __ATOMIC_RELAXED, __HIP_MEMORY_SCOPE_AGENT);
    }
}

__launch_bounds__(256, 1)
__global__ void lstm_main(const float* __restrict__ x,
                          const float* __restrict__ wxh0, const float* __restrict__ whh0,
                          const float* __restrict__ wxh1, const float* __restrict__ whh1,
                          const float* __restrict__ bx0, const float* __restrict__ bh0,
                          const float* __restrict__ bx1, const float* __restrict__ bh1,
                          float* __restrict__ out,
                          unsigned short* __restrict__ h0b,
                          unsigned short* __restrict__ h1b,
                          int* __restrict__ flags, int nslot) {
    extern __shared__ char smem[];
    const int layer = blockIdx.x >> 5;        // 0 or 1
    const int cb    = blockIdx.x & 31;        // owns h cols [cb*16, cb*16+16)
    const int wv    = threadIdx.x >> 6;       // wave -> row tile [16*wv, 16*wv+16)
    const int lane  = threadIdx.x & 63;
    const int quad  = lane >> 4;
    const int ln    = lane & 15;
    const int row0  = wv << 4;
    const int colh  = (cb << 4) + ln;

    // ---- stage weight slices into LDS (fp32 -> bf16 during staging) ----
    const int I0 = (layer == 0) ? 8 : 16;     // x-side K/32
    const int K0 = (layer == 0) ? In : Hn;
    const float* Wxs = (layer == 0) ? wxh0 : wxh1;
    const float* Whs = (layer == 0) ? whh0 : whh1;
    u64* sm64 = (u64*)smem;
    const int tot0 = I0 * 4 * 64;
    for (int c = threadIdx.x; c < tot0; c += 256) {
        int lc = c & 63, qg = (c >> 6) & 3, ii = c >> 8;
        const float* src = Wxs + (size_t)(qg * Hn + (cb << 4) + (lc & 15)) * K0
                               + ii * 32 + (lc >> 4) * 8;
        f32x4 s0 = *(const f32x4*)src;
        f32x4 s1 = *(const f32x4*)(src + 4);
        u64 lo = (u64)f2bf(s0[0]) | ((u64)f2bf(s0[1]) << 16) |
                 ((u64)f2bf(s0[2]) << 32) | ((u64)f2bf(s0[3]) << 48);
        u64 hi = (u64)f2bf(s1[0]) | ((u64)f2bf(s1[1]) << 16) |
                 ((u64)f2bf(s1[2]) << 32) | ((u64)f2bf(s1[3]) << 48);
        sm64[c * 2] = lo; sm64[c * 2 + 1] = hi;
    }
    const int hbase = tot0;
    for (int c = threadIdx.x; c < 16 * 4 * 64; c += 256) {
        int lc = c & 63, qg = (c >> 6) & 3, ii = c >> 8;
        const float* src = Whs + (size_t)(qg * Hn + (cb << 4) + (lc & 15)) * Hn
                               + ii * 32 + (lc >> 4) * 8;
        f32x4 s0 = *(const f32x4*)src;
        f32x4 s1 = *(const f32x4*)(src + 4);
        u64 lo = (u64)f2bf(s0[0]) | ((u64)f2bf(s0[1]) << 16) |
                 ((u64)f2bf(s0[2]) << 32) | ((u64)f2bf(s0[3]) << 48);
        u64 hi = (u64)f2bf(s1[0]) | ((u64)f2bf(s1[1]) << 16) |
                 ((u64)f2bf(s1[2]) << 32) | ((u64)f2bf(s1[3]) << 48);
        sm64[(hbase + c) * 2] = lo; sm64[(hbase + c) * 2 + 1] = hi;
    }
    __syncthreads();                          // the ONLY block-wide sync
    const bf16x8* bfr = (const bf16x8*)smem;

    float bias[4];
#pragma unroll
    for (int q = 0; q < 4; ++q) {
        int gc = q * Hn + colh;
        bias[q] = (layer == 0) ? (bx0[gc] + bh0[gc]) : (bx1[gc] + bh1[gc]);
    }

    const float* xrow0 = x + (size_t)(row0 + ln) * Tn * In + quad * 8;
    const int hoff = (row0 + ln) * Hn + quad * 8;   // *2B -> 16B aligned

    // flag topology: flag0[b][w] at flags[b*4+w]; flag1 at flags[128+b*4+w].
    // wave (layer,cb,wv) publishes flags[layer*128 + cb*4 + wv] = steps done.
    // consumer wave wv: lane<32 watches flag0[lane][wv], else flag1[lane-32][wv]
    // (row-tiles align: wave wv only ever consumes rows produced by waves wv).
    const int* spin_fp = flags + ((lane < 32) ? (lane * 4 + wv)
                                              : (128 + (lane - 32) * 4 + wv));
    int* pub_fp = flags + layer * 128 + cb * 4 + wv;

    float c[4] = {0.f, 0.f, 0.f, 0.f};
    int rs = 0, wsl = 1;                      // slots: h(t-1) at rs, h(t) at wsl

    for (int t = 0; t < Tn; ++t) {
        // L0: issue x(t) loads before the spin — latency hides under the wait
        f32x4 xr[16];
        if (layer == 0) {
            const float* xp = xrow0 + (size_t)t * In;
#pragma unroll
            for (int i = 0; i < 8; ++i) {
                xr[2 * i]     = *(const f32x4*)(xp + i * 32);
                xr[2 * i + 1] = *(const f32x4*)(xp + i * 32 + 4);
            }
        }

        // ---- dataflow wait (per-wave, elastic; no __syncthreads) ----
        // L0 step t: needs flag0 >= t (h0(t-1) rows) and, for ring reuse,
        //            flag1 >= t+2-nslot (slot being overwritten fully consumed).
        // L1 step t: needs flag0 >= t+1 (h0(t)) and flag1 >= t (h1(t-1)).
        {
            int ta = layer ? (t + 1) : t;
            int tb = layer ? t : (t + 2 - nslot);
            int tgt = (lane < 32) ? ta : tb;
            int v;
            do { v = ld_flag(spin_fp); } while (!__all(v >= tgt));
        }
        asm volatile("" ::: "memory");        // no load hoisting above the spin

        f32x4 acc[4];
#pragma unroll
        for (int q = 0; q < 4; ++q) acc[q] = (f32x4){bias[q], bias[q], bias[q], bias[q]};

        if (layer == 0) {
            const unsigned short* hp = h0b + (size_t)rs * SLOT_ELEMS + hoff;
            f32x4 A[16];
            uint64_t va = (uint64_t)hp;
            GLD16(A, va);
            bf16x8 axc[8];
#pragma unroll
            for (int i = 0; i < 8; ++i) {
                f32x4 xa = xr[2 * i], xc = xr[2 * i + 1];
                axc[i][0] = (short)f2bf(xa[0]); axc[i][1] = (short)f2bf(xa[1]);
                axc[i][2] = (short)f2bf(xa[2]); axc[i][3] = (short)f2bf(xa[3]);
                axc[i][4] = (short)f2bf(xc[0]); axc[i][5] = (short)f2bf(xc[1]);
                axc[i][6] = (short)f2bf(xc[2]); axc[i][7] = (short)f2bf(xc[3]);
            }
#pragma unroll
            for (int i = 0; i < 8; ++i)
#pragma unroll
                for (int q = 0; q < 4; ++q)
                    acc[q] = __builtin_amdgcn_mfma_f32_16x16x32_bf16(
                        axc[i], bfr[(i * 4 + q) * 64 + lane], acc[q], 0, 0, 0);
#pragma unroll
            for (int i = 0; i < 16; ++i)
#pragma unroll
                for (int q = 0; q < 4; ++q)
                    acc[q] = __builtin_amdgcn_mfma_f32_16x16x32_bf16(
                        asbf(A[i]), bfr[hbase + (i * 4 + q) * 64 + lane], acc[q], 0, 0, 0);
        } else {
            const unsigned short* p0 = h0b + (size_t)wsl * SLOT_ELEMS + hoff;  // h0(t)
            const unsigned short* p1 = h1b + (size_t)rs  * SLOT_ELEMS + hoff;  // h1(t-1)
            f32x4 A[16], Bv[16];
            uint64_t va = (uint64_t)p0, vb = (uint64_t)p1;
            GLD32(A, Bv, va, vb);
#pragma unroll
            for (int i = 0; i < 16; ++i)
#pragma unroll
                for (int q = 0; q < 4; ++q)
                    acc[q] = __builtin_amdgcn_mfma_f32_16x16x32_bf16(
                        asbf(A[i]), bfr[(i * 4 + q) * 64 + lane], acc[q], 0, 0, 0);
#pragma unroll
            for (int i = 0; i < 16; ++i)
#pragma unroll
                for (int q = 0; q < 4; ++q)
                    acc[q] = __builtin_amdgcn_mfma_f32_16x16x32_bf16(
                        asbf(Bv[i]), bfr[hbase + (i * 4 + q) * 64 + lane], acc[q], 0, 0, 0);
        }

        // ---- LSTM cell epilogue; sc1 h stores (L3-coherent) ----
        unsigned short* hw = ((layer == 0) ? h0b : h1b) + (size_t)wsl * SLOT_ELEMS;
#pragma unroll
        for (int r = 0; r < 4; ++r) {
            int row = row0 + quad * 4 + r;
            float ig = sigm(acc[0][r]);
            float fg = sigm(acc[1][r]);
            float gg = tanhv(acc[2][r]);
            float og = sigm(acc[3][r]);
            float cy = c[r] * fg + ig * gg;
            float hy = og * tanhv(cy);
            c[r] = cy;
            stg_coh(hw + row * Hn + colh, f2bf(hy));
            if (layer == 1) out[(size_t)row * (Tn * Hn) + (size_t)t * Hn + colh] = hy;
            if (t == Tn - 1) {
                out[OUT_HT + layer * (Bn * Hn) + row * Hn + colh] = hy;
                out[OUT_CT + layer * (Bn * Hn) + row * Hn + colh] = cy;
            }
        }

        // publish: own stores at L3 (vmcnt drain), then flag — per wave only
        asm volatile("s_waitcnt vmcnt(0)" ::: "memory");
        if (lane == 0) st_flag(pub_fp, t + 1);

        rs = wsl;
        wsl = (wsl + 1 == nslot) ? 0 : wsl + 1;
    }
}

extern "C" void kernel_launch(void* const* d_in, const int* in_sizes, int n_in,
                              void* d_out, int out_size, void* d_ws, size_t ws_size,
                              hipStream_t stream) {
    const float* x    = (const float*)d_in[0];
    const float* wxh0 = (const float*)d_in[1];
    const float* bxh0 = (const float*)d_in[2];
    const float* whh0 = (const float*)d_in[3];
    const float* bhh0 = (const float*)d_in[4];
    const float* wxh1 = (const float*)d_in[5];
    const float* bxh1 = (const float*)d_in[6];
    const float* whh1 = (const float*)d_in[7];
    const float* bhh1 = (const float*)d_in[8];
    float* out = (float*)d_out;

    char* ws = (char*)d_ws;
    int* flags = (int*)ws;
    long nslot_l = (long)((ws_size - 4096) / (2 * (size_t)SLOT_ELEMS * 2));
    int nslot = (int)(nslot_l < 3 ? 3 : (nslot_l > Tn + 1 ? Tn + 1 : nslot_l));
    unsigned short* h0b = (unsigned short*)(ws + 4096);
    unsigned short* h1b = h0b + (size_t)nslot * SLOT_ELEMS;

    static int lds_attr_set = 0;
    if (!lds_attr_set) {
        hipFuncSetAttribute((const void*)lstm_main,
                            hipFuncAttributeMaxDynamicSharedMemorySize, LDS_BYTES);
        lds_attr_set = 1;
    }

    lstm_prep<<<dim3(32), dim3(256), 0, stream>>>((u64*)h0b, (u64*)h1b, flags);

    lstm_main<<<dim3(NBLK), dim3(256), LDS_BYTES, stream>>>(
        x, wxh0, whh0, wxh1, whh1, bxh0, bhh0, bxh1, bhh1,
        out, h0b, h1b, flags, nslot);
}